// Round 5
// baseline (90.895 us; speedup 1.0000x reference)
//
#include <hip/hip_runtime.h>

// Problem constants (match reference)
#define N_VOX      200000
#define N_CLUST    2000
#define CLUST_SIZE 100
#define N_EDGE     32000
#define N_FEAT     16

// Output: 6.4M points x 16 feats (fp32) = 409.6 MB -> purely write-BW-bound.
// Work item ("quad") = (point, 4-feature group): 25.6M quads.
// 4 consecutive threads own one point -> each wave's f32x4 stores form a
// dense 1 KiB contiguous block per chain (perfect coalescing).
//
// R4: PERSISTENT GRID. 2048 blocks x 256 threads (8 blocks/CU, full 32
// waves/CU), grid-stride loop, ILP-4 body (~12 iterations per thread).
// Rationale: R2/R3's 25-50K one-shot blocks each paid W-load + ~600cy
// gather-chain warm-up with no stores in flight, idling the store pipe
// between block generations. Persistent waves amortize that and let the
// compiler software-pipeline chains across iterations.
//
// Stores stay NONTEMPORAL: the 409.6 MB stream must not evict the ~5 MB
// gather working set (data/clusts/edge_index) from L2.

#define TOTAL_QUADS (N_EDGE * 2 * CLUST_SIZE * 4)   // 25,600,000
#define QUARTER     (TOTAL_QUADS / 4)               //  6,400,000
#define BLOCK       256
#define GRID        2048
#define NTHREADS    (GRID * BLOCK)                  // 524,288

typedef float f32x4 __attribute__((ext_vector_type(4)));

__global__ __launch_bounds__(BLOCK) void edge_enc_kernel(
    const float* __restrict__ data,        // [N_VOX, 5]
    const int*   __restrict__ clusts,      // [N_CLUST, CLUST_SIZE]
    const int*   __restrict__ edge_index,  // [2, N_EDGE]
    const float* __restrict__ W,           // [5, 16]
    float*       __restrict__ out)         // [N_EDGE*200, 16]
{
    const unsigned t  = blockIdx.x * BLOCK + threadIdx.x;   // 0 .. 524287
    const unsigned fb = t & 3u;   // NTHREADS % 4 == 0 -> fb constant per thread

    // W sub-columns for this fb: 5 x f32x4, loaded ONCE per wave lifetime.
    const f32x4* __restrict__ Wv = reinterpret_cast<const f32x4*>(W);
    const f32x4 w0 = Wv[0 * 4 + fb];
    const f32x4 w1 = Wv[1 * 4 + fb];
    const f32x4 w2 = Wv[2 * 4 + fb];
    const f32x4 w3 = Wv[3 * 4 + fb];
    const f32x4 w4 = Wv[4 * 4 + fb];

    // Grid-stride over the first quarter; each iteration also handles the
    // same index in the other three quarters (4 independent gather chains).
    for (unsigned w = t; w < (unsigned)QUARTER; w += (unsigned)NTHREADS) {

        unsigned p[4], e[4];
        int vox_addr_c[4];
        unsigned v[4], s[4];
#pragma unroll
        for (int k = 0; k < 4; ++k) {
            const unsigned g = w + (unsigned)(k * QUARTER);
            p[k] = g >> 2;
            e[k] = p[k] / 200u;                 // magic-mul
            const unsigned j = p[k] - e[k] * 200u;
            s[k] = (j >= 100u) ? 1u : 0u;
            v[k] = j - s[k] * 100u;
        }

        int c[4];
#pragma unroll
        for (int k = 0; k < 4; ++k)
            c[k] = edge_index[s[k] * N_EDGE + e[k]];

        int vox[4];
#pragma unroll
        for (int k = 0; k < 4; ++k)
            vox[k] = clusts[c[k] * CLUST_SIZE + (int)v[k]];

        float x0[4], x1[4], x2[4], x4[4];
#pragma unroll
        for (int k = 0; k < 4; ++k) {
            const float* dr = data + (size_t)vox[k] * 5;
            x0[k] = dr[0];
            x1[k] = dr[1];
            x2[k] = dr[2];
            x4[k] = dr[4];
        }

#pragma unroll
        for (int k = 0; k < 4; ++k) {
            const float x3 = (float)e[k];       // batch-id column := edge id
            f32x4 r;
#pragma unroll
            for (int q = 0; q < 4; ++q) {
                float a = fmaf(x0[k], w0[q], fmaf(x1[k], w1[q],
                          fmaf(x2[k], w2[q], fmaf(x3, w3[q], x4[k] * w4[q]))));
                r[q] = fmaxf(a, 0.0f);
            }
            __builtin_nontemporal_store(r,
                reinterpret_cast<f32x4*>(out + (size_t)p[k] * N_FEAT + fb * 4u));
        }
    }
}

extern "C" void kernel_launch(void* const* d_in, const int* in_sizes, int n_in,
                              void* d_out, int out_size, void* d_ws, size_t ws_size,
                              hipStream_t stream) {
    const float* data       = (const float*)d_in[0];
    const int*   clusts     = (const int*)d_in[1];
    const int*   edge_index = (const int*)d_in[2];
    const float* W          = (const float*)d_in[3];
    float*       out        = (float*)d_out;

    edge_enc_kernel<<<GRID, BLOCK, 0, stream>>>(data, clusts, edge_index, W, out);
}

// Round 6
// 78.357 us; speedup vs baseline: 1.1600x; 1.1600x over previous
//
#include <hip/hip_runtime.h>

// Problem constants (match reference)
#define N_VOX      200000
#define N_CLUST    2000
#define CLUST_SIZE 100
#define N_EDGE     32000
#define N_FEAT     16

// Output: 6.4M points x 16 fp32 feats = 409.6 MB -> write-BW-bound.
// R5 = R2's verified-best structure (ILP-2, LDS W, 50K one-shot blocks,
// nontemporal stores) + a REPACK pass:
//   pack4[v] = {data[v][0], data[v][1], data[v][2], data[v][4]}  (3.2 MB in d_ws)
// Rationale: hop-3 gather previously read an unaligned 20 B row (4-5 dword
// requests, ~31% of rows split two 64B lines) from a 4 MB table that is
// exactly one XCD's L2 -> steady-state L2 misses ~170 MB HBM reads (inferred
// from 85.3 us vs 61 us pure-write roofline). Packed: ONE aligned f32x4 per
// row, table 3.2 MB -> gather set (3.2+0.8+0.25 MB) fits per-XCD L2.

#define TOTAL_QUADS (N_EDGE * 2 * CLUST_SIZE * 4)   // 25,600,000
#define HALF_QUADS  (TOTAL_QUADS / 2)               // 12,800,000
#define BLOCK       256
#define GRID_MAIN   (HALF_QUADS / BLOCK)            // 50,000

typedef float f32x4 __attribute__((ext_vector_type(4)));

// ---------- repack: data[N_VOX,5] -> pack4[N_VOX] {c0,c1,c2,c4} ----------
__global__ __launch_bounds__(BLOCK) void repack_kernel(
    const float* __restrict__ data, f32x4* __restrict__ pack)
{
    const unsigned v = blockIdx.x * BLOCK + threadIdx.x;
    if (v < N_VOX) {
        const float* dr = data + (size_t)v * 5;
        f32x4 r = { dr[0], dr[1], dr[2], dr[4] };
        pack[v] = r;
    }
}

// ---------- main kernel (R2 structure) ----------
template <bool PACKED>
__global__ __launch_bounds__(BLOCK) void edge_enc_kernel(
    const float* __restrict__ data,        // [N_VOX, 5]
    const f32x4* __restrict__ pack,        // [N_VOX] packed rows (if PACKED)
    const int*   __restrict__ clusts,      // [N_CLUST, CLUST_SIZE]
    const int*   __restrict__ edge_index,  // [2, N_EDGE]
    const float* __restrict__ W,           // [5, 16]
    float*       __restrict__ out)         // [N_EDGE*200, 16]
{
    __shared__ float Ws[5 * N_FEAT];   // 80 floats
    if (threadIdx.x < 5 * N_FEAT) {
        Ws[threadIdx.x] = W[threadIdx.x];
    }
    __syncthreads();

    const unsigned t = blockIdx.x * BLOCK + threadIdx.x;    // 0 .. 12.8M-1

    // Both quads share fb since HALF_QUADS % 4 == 0.
    const unsigned fb    = t & 3u;
    const unsigned fbase = fb * 4u;

    float w0[4], w1[4], w2[4], w3[4], w4[4];
#pragma unroll
    for (int q = 0; q < 4; ++q) {
        w0[q] = Ws[0 * N_FEAT + fbase + q];
        w1[q] = Ws[1 * N_FEAT + fbase + q];
        w2[q] = Ws[2 * N_FEAT + fbase + q];
        w3[q] = Ws[3 * N_FEAT + fbase + q];
        w4[q] = Ws[4 * N_FEAT + fbase + q];
    }

    // ---- two independent index chains ----
    const unsigned p0 = t >> 2;
    const unsigned p1 = (t + (unsigned)HALF_QUADS) >> 2;

    const unsigned e0 = p0 / 200u;                 // magic-mul
    const unsigned e1 = p1 / 200u;
    const unsigned j0 = p0 - e0 * 200u;
    const unsigned j1 = p1 - e1 * 200u;
    const unsigned s0 = (j0 >= 100u) ? 1u : 0u;
    const unsigned s1 = (j1 >= 100u) ? 1u : 0u;
    const unsigned v0 = j0 - s0 * 100u;
    const unsigned v1 = j1 - s1 * 100u;

    const int c0 = edge_index[s0 * N_EDGE + e0];
    const int c1 = edge_index[s1 * N_EDGE + e1];

    const int vox0 = clusts[c0 * CLUST_SIZE + (int)v0];
    const int vox1 = clusts[c1 * CLUST_SIZE + (int)v1];

    float a0, a1, a2, a4, b0, b1, b2, b4;
    if (PACKED) {
        const f32x4 ra = pack[vox0];
        const f32x4 rb = pack[vox1];
        a0 = ra.x; a1 = ra.y; a2 = ra.z; a4 = ra.w;
        b0 = rb.x; b1 = rb.y; b2 = rb.z; b4 = rb.w;
    } else {
        const float* dr0 = data + (size_t)vox0 * 5;
        const float* dr1 = data + (size_t)vox1 * 5;
        a0 = dr0[0]; a1 = dr0[1]; a2 = dr0[2]; a4 = dr0[4];
        b0 = dr1[0]; b1 = dr1[1]; b2 = dr1[2]; b4 = dr1[4];
    }
    const float a3 = (float)e0;   // batch-id column := edge id
    const float b3 = (float)e1;

    float ra4[4], rb4[4];
#pragma unroll
    for (int q = 0; q < 4; ++q) {
        float va = fmaf(a0, w0[q], fmaf(a1, w1[q], fmaf(a2, w2[q],
                   fmaf(a3, w3[q], a4 * w4[q]))));
        float vb = fmaf(b0, w0[q], fmaf(b1, w1[q], fmaf(b2, w2[q],
                   fmaf(b3, w3[q], b4 * w4[q]))));
        ra4[q] = fmaxf(va, 0.0f);
        rb4[q] = fmaxf(vb, 0.0f);
    }

    f32x4 ova = { ra4[0], ra4[1], ra4[2], ra4[3] };
    f32x4 ovb = { rb4[0], rb4[1], rb4[2], rb4[3] };
    __builtin_nontemporal_store(ova,
        reinterpret_cast<f32x4*>(out + (size_t)p0 * N_FEAT + fbase));
    __builtin_nontemporal_store(ovb,
        reinterpret_cast<f32x4*>(out + (size_t)p1 * N_FEAT + fbase));
}

extern "C" void kernel_launch(void* const* d_in, const int* in_sizes, int n_in,
                              void* d_out, int out_size, void* d_ws, size_t ws_size,
                              hipStream_t stream) {
    const float* data       = (const float*)d_in[0];
    const int*   clusts     = (const int*)d_in[1];
    const int*   edge_index = (const int*)d_in[2];
    const float* W          = (const float*)d_in[3];
    float*       out        = (float*)d_out;

    const size_t pack_bytes = (size_t)N_VOX * sizeof(f32x4);   // 3.2 MB
    if (ws_size >= pack_bytes) {
        f32x4* pack = (f32x4*)d_ws;
        const int grid_rp = (N_VOX + BLOCK - 1) / BLOCK;       // 782
        repack_kernel<<<grid_rp, BLOCK, 0, stream>>>(data, pack);
        edge_enc_kernel<true><<<GRID_MAIN, BLOCK, 0, stream>>>(
            data, pack, clusts, edge_index, W, out);
    } else {
        edge_enc_kernel<false><<<GRID_MAIN, BLOCK, 0, stream>>>(
            data, nullptr, clusts, edge_index, W, out);
    }
}